// Round 1
// baseline (5319.229 us; speedup 1.0000x reference)
//
#include <hip/hip_runtime.h>

#define T_LEN 16384
#define B_SZ  256
#define NCHUNK (T_LEN / 4)

__device__ __forceinline__ float ex2(float x) { return __builtin_amdgcn_exp2f(x); }
__device__ __forceinline__ float rcpf(float x) { return __builtin_amdgcn_rcpf(x); }

__device__ __forceinline__ float4 rev4(float4 v) {
    float4 o; o.x = v.w; o.y = v.z; o.z = v.y; o.w = v.x; return o;
}

// One GRU step, H=1.
// preR, preZ: input-gate precursors pre-scaled by -log2(e) (biases folded in)
// preN:       input n-gate precursor pre-scaled by +2*log2(e)
// UR, UZ pre-scaled by -log2(e); UN2, DN2 pre-scaled by +2*log2(e)
// Critical chain: fma -> exp2 -> add -> rcp -> fma -> exp2 -> add -> rcp -> fma -> fma
__device__ __forceinline__ float gru_step(float h, float preR, float preZ, float preN,
                                          float UR, float UZ, float UN2, float DN2)
{
    float er  = ex2(fmaf(h, UR, preR));
    float ez  = ex2(fmaf(h, UZ, preZ));
    float r   = rcpf(1.0f + er);
    float z   = rcpf(1.0f + ez);
    float hn2 = fmaf(h, UN2, DN2);          // off critical path (ready early)
    float en  = ex2(fmaf(r, hn2, preN));
    float n   = fmaf(-2.0f, rcpf(1.0f + en), 1.0f);   // tanh(y) = 1 - 2/(1+e^{2y})
    float omz = 1.0f - z;                   // ready before n
    float zh  = z * h;                      // ready before n
    return fmaf(n, omz, zh);                // single fma after n
}

// ---------------- Layer 0 scan (input: x[b][t], single stream) ----------------
template<bool REV>
__device__ void scan_l0_dir(const float* __restrict__ x,
                            const float* __restrict__ wih, const float* __restrict__ whh,
                            const float* __restrict__ bih, const float* __restrict__ bhh,
                            float* __restrict__ out, int b)
{
    const int d = REV ? 1 : 0;
    const float L2E = 1.4426950408889634f;
    const float WR  = -L2E * wih[d*3+0];
    const float WZ  = -L2E * wih[d*3+1];
    const float WN  =  2.0f*L2E * wih[d*3+2];
    const float UR  = -L2E * whh[d*3+0];
    const float UZ  = -L2E * whh[d*3+1];
    const float UN2 =  2.0f*L2E * whh[d*3+2];
    const float CR  = -L2E * (bih[d*3+0] + bhh[d*3+0]);
    const float CZ  = -L2E * (bih[d*3+1] + bhh[d*3+1]);
    const float CN  =  2.0f*L2E * bih[d*3+2];
    const float DN2 =  2.0f*L2E * bhh[d*3+2];

    const float4* xin = (const float4*)(x + (size_t)b * T_LEN);
    float4* op = (float4*)(out + ((size_t)d * B_SZ + b) * T_LEN);

    auto LD = [&](int c) -> float4 {
        int pc = REV ? (NCHUNK - 1 - c) : c;
        float4 v = xin[pc];
        return REV ? rev4(v) : v;
    };

    // prefetch depth 4 chunks = 16 steps (~900 cyc of chain) ahead
    float4 p0 = LD(0), p1 = LD(1), p2 = LD(2), p3 = LD(3);
    float h = 0.0f;
    for (int c = 0; c < NCHUNK; ++c) {
        float4 cur = p0;
        p0 = p1; p1 = p2; p2 = p3;
        if (c + 4 < NCHUNK) p3 = LD(c + 4);
        float4 o;
        h = gru_step(h, fmaf(cur.x, WR, CR), fmaf(cur.x, WZ, CZ), fmaf(cur.x, WN, CN), UR, UZ, UN2, DN2); o.x = h;
        h = gru_step(h, fmaf(cur.y, WR, CR), fmaf(cur.y, WZ, CZ), fmaf(cur.y, WN, CN), UR, UZ, UN2, DN2); o.y = h;
        h = gru_step(h, fmaf(cur.z, WR, CR), fmaf(cur.z, WZ, CZ), fmaf(cur.z, WN, CN), UR, UZ, UN2, DN2); o.z = h;
        h = gru_step(h, fmaf(cur.w, WR, CR), fmaf(cur.w, WZ, CZ), fmaf(cur.w, WN, CN), UR, UZ, UN2, DN2); o.w = h;
        int pc = REV ? (NCHUNK - 1 - c) : c;
        op[pc] = REV ? rev4(o) : o;
    }
}

// ------------- Layers 1/2 scan (input: [dir][b][t], two streams) -------------
template<bool REV>
__device__ void scan_l12_dir(const float* __restrict__ in,
                             const float* __restrict__ wih, const float* __restrict__ whh,
                             const float* __restrict__ bih, const float* __restrict__ bhh,
                             float* __restrict__ out, int b)
{
    const int d = REV ? 1 : 0;
    const float L2E = 1.4426950408889634f;
    const float WR0 = -L2E * wih[(d*3+0)*2+0], WR1 = -L2E * wih[(d*3+0)*2+1];
    const float WZ0 = -L2E * wih[(d*3+1)*2+0], WZ1 = -L2E * wih[(d*3+1)*2+1];
    const float WN0 =  2.0f*L2E * wih[(d*3+2)*2+0], WN1 = 2.0f*L2E * wih[(d*3+2)*2+1];
    const float UR  = -L2E * whh[d*3+0];
    const float UZ  = -L2E * whh[d*3+1];
    const float UN2 =  2.0f*L2E * whh[d*3+2];
    const float CR  = -L2E * (bih[d*3+0] + bhh[d*3+0]);
    const float CZ  = -L2E * (bih[d*3+1] + bhh[d*3+1]);
    const float CN  =  2.0f*L2E * bih[d*3+2];
    const float DN2 =  2.0f*L2E * bhh[d*3+2];

    const float4* inf = (const float4*)(in + (size_t)b * T_LEN);
    const float4* inb = (const float4*)(in + ((size_t)B_SZ + b) * T_LEN);
    float4* op = (float4*)(out + ((size_t)d * B_SZ + b) * T_LEN);

    auto LDF = [&](int c) -> float4 {
        int pc = REV ? (NCHUNK - 1 - c) : c;
        float4 v = inf[pc];
        return REV ? rev4(v) : v;
    };
    auto LDB = [&](int c) -> float4 {
        int pc = REV ? (NCHUNK - 1 - c) : c;
        float4 v = inb[pc];
        return REV ? rev4(v) : v;
    };

    float4 f0 = LDF(0), f1 = LDF(1), f2 = LDF(2), f3 = LDF(3);
    float4 g0 = LDB(0), g1 = LDB(1), g2 = LDB(2), g3 = LDB(3);
    float h = 0.0f;
    for (int c = 0; c < NCHUNK; ++c) {
        float4 cf = f0, cg = g0;
        f0 = f1; f1 = f2; f2 = f3;
        g0 = g1; g1 = g2; g2 = g3;
        if (c + 4 < NCHUNK) { f3 = LDF(c + 4); g3 = LDB(c + 4); }
        float4 o;
        {
            float pr = fmaf(cf.x, WR0, fmaf(cg.x, WR1, CR));
            float pz = fmaf(cf.x, WZ0, fmaf(cg.x, WZ1, CZ));
            float pn = fmaf(cf.x, WN0, fmaf(cg.x, WN1, CN));
            h = gru_step(h, pr, pz, pn, UR, UZ, UN2, DN2); o.x = h;
        }
        {
            float pr = fmaf(cf.y, WR0, fmaf(cg.y, WR1, CR));
            float pz = fmaf(cf.y, WZ0, fmaf(cg.y, WZ1, CZ));
            float pn = fmaf(cf.y, WN0, fmaf(cg.y, WN1, CN));
            h = gru_step(h, pr, pz, pn, UR, UZ, UN2, DN2); o.y = h;
        }
        {
            float pr = fmaf(cf.z, WR0, fmaf(cg.z, WR1, CR));
            float pz = fmaf(cf.z, WZ0, fmaf(cg.z, WZ1, CZ));
            float pn = fmaf(cf.z, WN0, fmaf(cg.z, WN1, CN));
            h = gru_step(h, pr, pz, pn, UR, UZ, UN2, DN2); o.z = h;
        }
        {
            float pr = fmaf(cf.w, WR0, fmaf(cg.w, WR1, CR));
            float pz = fmaf(cf.w, WZ0, fmaf(cg.w, WZ1, CZ));
            float pn = fmaf(cf.w, WN0, fmaf(cg.w, WN1, CN));
            h = gru_step(h, pr, pz, pn, UR, UZ, UN2, DN2); o.w = h;
        }
        int pc = REV ? (NCHUNK - 1 - c) : c;
        op[pc] = REV ? rev4(o) : o;
    }
}

// 8 blocks x 64 threads: blocks 0..3 forward (b = blk*64+tid), 4..7 backward.
// One wave per SIMD -> no issue contention on the latency chain.
__global__ void __launch_bounds__(64) k_scan_l0(const float* __restrict__ x,
                                                const float* __restrict__ wih,
                                                const float* __restrict__ whh,
                                                const float* __restrict__ bih,
                                                const float* __restrict__ bhh,
                                                float* __restrict__ out)
{
    int b = (blockIdx.x & 3) * 64 + threadIdx.x;
    if (blockIdx.x < 4) scan_l0_dir<false>(x, wih, whh, bih, bhh, out, b);
    else                scan_l0_dir<true >(x, wih, whh, bih, bhh, out, b);
}

__global__ void __launch_bounds__(64) k_scan_l12(const float* __restrict__ in,
                                                 const float* __restrict__ wih,
                                                 const float* __restrict__ whh,
                                                 const float* __restrict__ bih,
                                                 const float* __restrict__ bhh,
                                                 float* __restrict__ out)
{
    int b = (blockIdx.x & 3) * 64 + threadIdx.x;
    if (blockIdx.x < 4) scan_l12_dir<false>(in, wih, whh, bih, bhh, out, b);
    else                scan_l12_dir<true >(in, wih, whh, bih, bhh, out, b);
}

// y[b][0][t] = wf * h2[0][b][t] + wb * h2[1][b][t] + bias  (fully coalesced float4)
__global__ void __launch_bounds__(256) k_proj(const float* __restrict__ h2,
                                              const float* __restrict__ wo,
                                              const float* __restrict__ bo,
                                              float* __restrict__ y)
{
    int gid = blockIdx.x * 256 + threadIdx.x;      // 0 .. B*NCHUNK-1
    int b = gid / NCHUNK, t4 = gid % NCHUNK;
    const float wf = wo[0], wb = wo[1], bias = bo[0];
    float4 f = *(const float4*)(h2 + (size_t)b * T_LEN + 4 * t4);
    float4 g = *(const float4*)(h2 + ((size_t)B_SZ + b) * T_LEN + 4 * t4);
    float4 o;
    o.x = fmaf(wf, f.x, fmaf(wb, g.x, bias));
    o.y = fmaf(wf, f.y, fmaf(wb, g.y, bias));
    o.z = fmaf(wf, f.z, fmaf(wb, g.z, bias));
    o.w = fmaf(wf, f.w, fmaf(wb, g.w, bias));
    *(float4*)(y + (size_t)b * T_LEN + 4 * t4) = o;
}

extern "C" void kernel_launch(void* const* d_in, const int* in_sizes, int n_in,
                              void* d_out, int out_size, void* d_ws, size_t ws_size,
                              hipStream_t stream)
{
    (void)in_sizes; (void)n_in; (void)out_size; (void)ws_size;
    const float* x      = (const float*)d_in[0];
    const float* w_ih0  = (const float*)d_in[1];
    const float* w_hh0  = (const float*)d_in[2];
    const float* b_ih0  = (const float*)d_in[3];
    const float* b_hh0  = (const float*)d_in[4];
    const float* w_ih12 = (const float*)d_in[5];   // (2,2,3,2)
    const float* w_hh12 = (const float*)d_in[6];   // (2,2,3,1)
    const float* b_ih12 = (const float*)d_in[7];   // (2,2,3)
    const float* b_hh12 = (const float*)d_in[8];   // (2,2,3)
    const float* w_out  = (const float*)d_in[9];
    const float* b_out  = (const float*)d_in[10];
    float* y = (float*)d_out;

    // ws: buf0 [2][B][T] fp32 (33.5 MB), buf1 same. Layer2 output reuses buf0.
    float* buf0 = (float*)d_ws;
    float* buf1 = buf0 + (size_t)2 * B_SZ * T_LEN;

    k_scan_l0 <<<8, 64, 0, stream>>>(x,    w_ih0,       w_hh0,      b_ih0,      b_hh0,      buf0);
    k_scan_l12<<<8, 64, 0, stream>>>(buf0, w_ih12 + 0,  w_hh12 + 0, b_ih12 + 0, b_hh12 + 0, buf1);
    k_scan_l12<<<8, 64, 0, stream>>>(buf1, w_ih12 + 12, w_hh12 + 6, b_ih12 + 6, b_hh12 + 6, buf0);
    k_proj    <<<4096, 256, 0, stream>>>(buf0, w_out, b_out, y);
}

// Round 2
// 378.334 us; speedup vs baseline: 14.0596x; 14.0596x over previous
//
#include <hip/hip_runtime.h>

#define T_LEN 16384
#define B_SZ  256
#define S_CH  64                 // time chunks per direction
#define CL    (T_LEN / S_CH)     // 256 stored steps per chunk
#define HALO  1024               // burn-in steps (contractive recurrence)

__device__ __forceinline__ float ex2(float x)  { return __builtin_amdgcn_exp2f(x); }
__device__ __forceinline__ float rcpf(float x) { return __builtin_amdgcn_rcpf(x); }

// One GRU step, H=1. Weights pre-scaled: UR,UZ by -log2e; UN2,DN2 by +2log2e.
// Critical chain: fma -> exp2 -> add -> rcp -> fma -> exp2 -> add -> rcp -> fma -> fma
__device__ __forceinline__ float gru_step(float h, float preR, float preZ, float preN,
                                          float UR, float UZ, float UN2, float DN2)
{
    float er  = ex2(fmaf(h, UR, preR));
    float ez  = ex2(fmaf(h, UZ, preZ));
    float r   = rcpf(1.0f + er);
    float z   = rcpf(1.0f + ez);
    float hn2 = fmaf(h, UN2, DN2);                    // off critical path
    float en  = ex2(fmaf(r, hn2, preN));
    float n   = fmaf(-2.0f, rcpf(1.0f + en), 1.0f);   // tanh via exp2
    float omz = 1.0f - z;
    float zh  = z * h;
    return fmaf(n, omz, zh);
}

__device__ __forceinline__ void load16(float* dst, const float* row, int low) {
    const float4* p = (const float4*)(row + low);
    float4 a = p[0], b = p[1], c = p[2], d = p[3];
    dst[0]=a.x;  dst[1]=a.y;  dst[2]=a.z;  dst[3]=a.w;
    dst[4]=b.x;  dst[5]=b.y;  dst[6]=b.z;  dst[7]=b.w;
    dst[8]=c.x;  dst[9]=c.y;  dst[10]=c.z; dst[11]=c.w;
    dst[12]=d.x; dst[13]=d.y; dst[14]=d.z; dst[15]=d.w;
}

__device__ __forceinline__ void store16(float* row, int low, const float* o) {
    float4* q = (float4*)(row + low);
    q[0] = make_float4(o[0],  o[1],  o[2],  o[3]);
    q[1] = make_float4(o[4],  o[5],  o[6],  o[7]);
    q[2] = make_float4(o[8],  o[9],  o[10], o[11]);
    q[3] = make_float4(o[12], o[13], o[14], o[15]);
}

// ---------------- Layer 0: input x[b][t], single stream ----------------
template<bool REV>
__device__ void scan_l0_dir(const float* __restrict__ x,
                            const float* __restrict__ wih, const float* __restrict__ whh,
                            const float* __restrict__ bih, const float* __restrict__ bhh,
                            float* __restrict__ out, int b, int s)
{
    const int d = REV ? 1 : 0;
    const float L2E = 1.4426950408889634f;
    const float WR  = -L2E * wih[d*3+0];
    const float WZ  = -L2E * wih[d*3+1];
    const float WN  =  2.0f*L2E * wih[d*3+2];
    const float UR  = -L2E * whh[d*3+0];
    const float UZ  = -L2E * whh[d*3+1];
    const float UN2 =  2.0f*L2E * whh[d*3+2];
    const float CR  = -L2E * (bih[d*3+0] + bhh[d*3+0]);
    const float CZ  = -L2E * (bih[d*3+1] + bhh[d*3+1]);
    const float CN  =  2.0f*L2E * bih[d*3+2];
    const float DN2 =  2.0f*L2E * bhh[d*3+2];

    int warm, low0;
    if (!REV) { warm = min(HALO, s * CL);               low0 = s * CL - warm; }
    else      { warm = min(HALO, T_LEN - (s + 1) * CL); low0 = (s + 1) * CL + warm - 16; }
    const int nsup = (warm + CL) >> 4;
    const int warm_sup = warm >> 4;

    const float* xrow = x + (size_t)b * T_LEN;
    float* orow = out + ((size_t)d * B_SZ + b) * T_LEN;

    float cur[16];
    load16(cur, xrow, low0);
    float h = 0.0f;
    int low = low0;
    for (int i = 0; i < nsup; ++i) {
        int nlow = REV ? low - 16 : low + 16;
        int cln  = min(max(nlow, 0), T_LEN - 16);   // unconditional clamped prefetch
        float nxt[16];
        load16(nxt, xrow, cln);
        float o[16];
        #pragma unroll
        for (int jj = 0; jj < 16; ++jj) {
            int j = REV ? 15 - jj : jj;
            float xv = cur[j];
            h = gru_step(h, fmaf(xv, WR, CR), fmaf(xv, WZ, CZ), fmaf(xv, WN, CN),
                         UR, UZ, UN2, DN2);
            o[j] = h;
        }
        if (i >= warm_sup) store16(orow, low, o);   // wave-uniform branch
        #pragma unroll
        for (int k = 0; k < 16; ++k) cur[k] = nxt[k];
        low = nlow;
    }
}

// ------------- Layers 1/2: input [dir][b][t], two streams -------------
template<bool REV>
__device__ void scan_l12_dir(const float* __restrict__ in,
                             const float* __restrict__ wih, const float* __restrict__ whh,
                             const float* __restrict__ bih, const float* __restrict__ bhh,
                             float* __restrict__ out, int b, int s)
{
    const int d = REV ? 1 : 0;
    const float L2E = 1.4426950408889634f;
    const float WR0 = -L2E * wih[(d*3+0)*2+0], WR1 = -L2E * wih[(d*3+0)*2+1];
    const float WZ0 = -L2E * wih[(d*3+1)*2+0], WZ1 = -L2E * wih[(d*3+1)*2+1];
    const float WN0 =  2.0f*L2E * wih[(d*3+2)*2+0], WN1 = 2.0f*L2E * wih[(d*3+2)*2+1];
    const float UR  = -L2E * whh[d*3+0];
    const float UZ  = -L2E * whh[d*3+1];
    const float UN2 =  2.0f*L2E * whh[d*3+2];
    const float CR  = -L2E * (bih[d*3+0] + bhh[d*3+0]);
    const float CZ  = -L2E * (bih[d*3+1] + bhh[d*3+1]);
    const float CN  =  2.0f*L2E * bih[d*3+2];
    const float DN2 =  2.0f*L2E * bhh[d*3+2];

    int warm, low0;
    if (!REV) { warm = min(HALO, s * CL);               low0 = s * CL - warm; }
    else      { warm = min(HALO, T_LEN - (s + 1) * CL); low0 = (s + 1) * CL + warm - 16; }
    const int nsup = (warm + CL) >> 4;
    const int warm_sup = warm >> 4;

    const float* frow = in + (size_t)b * T_LEN;
    const float* grow = in + ((size_t)B_SZ + b) * T_LEN;
    float* orow = out + ((size_t)d * B_SZ + b) * T_LEN;

    float cf[16], cg[16];
    load16(cf, frow, low0);
    load16(cg, grow, low0);
    float h = 0.0f;
    int low = low0;
    for (int i = 0; i < nsup; ++i) {
        int nlow = REV ? low - 16 : low + 16;
        int cln  = min(max(nlow, 0), T_LEN - 16);
        float nf[16], ng[16];
        load16(nf, frow, cln);
        load16(ng, grow, cln);
        float o[16];
        #pragma unroll
        for (int jj = 0; jj < 16; ++jj) {
            int j = REV ? 15 - jj : jj;
            float a = cf[j], g2 = cg[j];
            float pr = fmaf(a, WR0, fmaf(g2, WR1, CR));
            float pz = fmaf(a, WZ0, fmaf(g2, WZ1, CZ));
            float pn = fmaf(a, WN0, fmaf(g2, WN1, CN));
            h = gru_step(h, pr, pz, pn, UR, UZ, UN2, DN2);
            o[j] = h;
        }
        if (i >= warm_sup) store16(orow, low, o);
        #pragma unroll
        for (int k = 0; k < 16; ++k) { cf[k] = nf[k]; cg[k] = ng[k]; }
        low = nlow;
    }
}

// Grid 512 x 64: blockIdx bits [1:0]=batch group, [7:2]=chunk, [8]=direction.
__global__ void __launch_bounds__(64) k_scan_l0(const float* __restrict__ x,
                                                const float* __restrict__ wih,
                                                const float* __restrict__ whh,
                                                const float* __restrict__ bih,
                                                const float* __restrict__ bhh,
                                                float* __restrict__ out)
{
    int b = (blockIdx.x & 3) * 64 + threadIdx.x;
    int s = (blockIdx.x >> 2) & (S_CH - 1);
    if (blockIdx.x < 256) scan_l0_dir<false>(x, wih, whh, bih, bhh, out, b, s);
    else                  scan_l0_dir<true >(x, wih, whh, bih, bhh, out, b, s);
}

__global__ void __launch_bounds__(64) k_scan_l12(const float* __restrict__ in,
                                                 const float* __restrict__ wih,
                                                 const float* __restrict__ whh,
                                                 const float* __restrict__ bih,
                                                 const float* __restrict__ bhh,
                                                 float* __restrict__ out)
{
    int b = (blockIdx.x & 3) * 64 + threadIdx.x;
    int s = (blockIdx.x >> 2) & (S_CH - 1);
    if (blockIdx.x < 256) scan_l12_dir<false>(in, wih, whh, bih, bhh, out, b, s);
    else                  scan_l12_dir<true >(in, wih, whh, bih, bhh, out, b, s);
}

// y[b][0][t] = wf * h2[0][b][t] + wb * h2[1][b][t] + bias
__global__ void __launch_bounds__(256) k_proj(const float* __restrict__ h2,
                                              const float* __restrict__ wo,
                                              const float* __restrict__ bo,
                                              float* __restrict__ y)
{
    int gid = blockIdx.x * 256 + threadIdx.x;
    int b = gid / (T_LEN / 4), t4 = gid % (T_LEN / 4);
    const float wf = wo[0], wb = wo[1], bias = bo[0];
    float4 f = *(const float4*)(h2 + (size_t)b * T_LEN + 4 * t4);
    float4 g = *(const float4*)(h2 + ((size_t)B_SZ + b) * T_LEN + 4 * t4);
    float4 o;
    o.x = fmaf(wf, f.x, fmaf(wb, g.x, bias));
    o.y = fmaf(wf, f.y, fmaf(wb, g.y, bias));
    o.z = fmaf(wf, f.z, fmaf(wb, g.z, bias));
    o.w = fmaf(wf, f.w, fmaf(wb, g.w, bias));
    *(float4*)(y + (size_t)b * T_LEN + 4 * t4) = o;
}

extern "C" void kernel_launch(void* const* d_in, const int* in_sizes, int n_in,
                              void* d_out, int out_size, void* d_ws, size_t ws_size,
                              hipStream_t stream)
{
    (void)in_sizes; (void)n_in; (void)out_size; (void)ws_size;
    const float* x      = (const float*)d_in[0];
    const float* w_ih0  = (const float*)d_in[1];
    const float* w_hh0  = (const float*)d_in[2];
    const float* b_ih0  = (const float*)d_in[3];
    const float* b_hh0  = (const float*)d_in[4];
    const float* w_ih12 = (const float*)d_in[5];   // (2,2,3,2)
    const float* w_hh12 = (const float*)d_in[6];   // (2,2,3,1)
    const float* b_ih12 = (const float*)d_in[7];   // (2,2,3)
    const float* b_hh12 = (const float*)d_in[8];   // (2,2,3)
    const float* w_out  = (const float*)d_in[9];
    const float* b_out  = (const float*)d_in[10];
    float* y = (float*)d_out;

    float* buf0 = (float*)d_ws;                          // [2][B][T]
    float* buf1 = buf0 + (size_t)2 * B_SZ * T_LEN;       // [2][B][T]

    k_scan_l0 <<<512, 64, 0, stream>>>(x,    w_ih0,       w_hh0,      b_ih0,      b_hh0,      buf0);
    k_scan_l12<<<512, 64, 0, stream>>>(buf0, w_ih12 + 0,  w_hh12 + 0, b_ih12 + 0, b_hh12 + 0, buf1);
    k_scan_l12<<<512, 64, 0, stream>>>(buf1, w_ih12 + 12, w_hh12 + 6, b_ih12 + 6, b_hh12 + 6, buf0);
    k_proj    <<<4096, 256, 0, stream>>>(buf0, w_out, b_out, y);
}

// Round 3
// 269.236 us; speedup vs baseline: 19.7568x; 1.4052x over previous
//
#include <hip/hip_runtime.h>

#define T_LEN 16384
#define B_SZ  256
#define S_CH  256                // time chunks per direction
#define CL    (T_LEN / S_CH)     // 64 stored steps per chunk
#define HALO  256                // burn-in steps (contractive recurrence)

__device__ __forceinline__ float ex2(float x)  { return __builtin_amdgcn_exp2f(x); }
__device__ __forceinline__ float rcpf(float x) { return __builtin_amdgcn_rcpf(x); }

// One GRU step, H=1. Weights pre-scaled: UR,UZ by -log2e; UN2,DN2 by +2log2e.
// Critical chain: fma -> exp2 -> add -> rcp -> fma -> exp2 -> add -> rcp -> fma -> fma
__device__ __forceinline__ float gru_step(float h, float preR, float preZ, float preN,
                                          float UR, float UZ, float UN2, float DN2)
{
    float er  = ex2(fmaf(h, UR, preR));
    float ez  = ex2(fmaf(h, UZ, preZ));
    float r   = rcpf(1.0f + er);
    float z   = rcpf(1.0f + ez);
    float hn2 = fmaf(h, UN2, DN2);                    // off critical path
    float en  = ex2(fmaf(r, hn2, preN));
    float n   = fmaf(-2.0f, rcpf(1.0f + en), 1.0f);   // tanh via exp2
    float omz = 1.0f - z;
    float zh  = z * h;
    return fmaf(n, omz, zh);
}

__device__ __forceinline__ void load16(float* dst, const float* row, int low) {
    const float4* p = (const float4*)(row + low);
    float4 a = p[0], b = p[1], c = p[2], d = p[3];
    dst[0]=a.x;  dst[1]=a.y;  dst[2]=a.z;  dst[3]=a.w;
    dst[4]=b.x;  dst[5]=b.y;  dst[6]=b.z;  dst[7]=b.w;
    dst[8]=c.x;  dst[9]=c.y;  dst[10]=c.z; dst[11]=c.w;
    dst[12]=d.x; dst[13]=d.y; dst[14]=d.z; dst[15]=d.w;
}

__device__ __forceinline__ void store16(float* row, int low, const float* o) {
    float4* q = (float4*)(row + low);
    q[0] = make_float4(o[0],  o[1],  o[2],  o[3]);
    q[1] = make_float4(o[4],  o[5],  o[6],  o[7]);
    q[2] = make_float4(o[8],  o[9],  o[10], o[11]);
    q[3] = make_float4(o[12], o[13], o[14], o[15]);
}

// ---------------- Layer 0: input x[b][t], single stream ----------------
template<bool REV>
__device__ void scan_l0_dir(const float* __restrict__ x,
                            const float* __restrict__ wih, const float* __restrict__ whh,
                            const float* __restrict__ bih, const float* __restrict__ bhh,
                            float* __restrict__ out, int b, int s)
{
    const int d = REV ? 1 : 0;
    const float L2E = 1.4426950408889634f;
    const float WR  = -L2E * wih[d*3+0];
    const float WZ  = -L2E * wih[d*3+1];
    const float WN  =  2.0f*L2E * wih[d*3+2];
    const float UR  = -L2E * whh[d*3+0];
    const float UZ  = -L2E * whh[d*3+1];
    const float UN2 =  2.0f*L2E * whh[d*3+2];
    const float CR  = -L2E * (bih[d*3+0] + bhh[d*3+0]);
    const float CZ  = -L2E * (bih[d*3+1] + bhh[d*3+1]);
    const float CN  =  2.0f*L2E * bih[d*3+2];
    const float DN2 =  2.0f*L2E * bhh[d*3+2];

    int warm, low0;
    if (!REV) { warm = min(HALO, s * CL);               low0 = s * CL - warm; }
    else      { warm = min(HALO, T_LEN - (s + 1) * CL); low0 = (s + 1) * CL + warm - 16; }
    const int nsup = (warm + CL) >> 4;
    const int warm_sup = warm >> 4;

    const float* xrow = x + (size_t)b * T_LEN;
    float* orow = out + ((size_t)d * B_SZ + b) * T_LEN;

    float cur[16];
    load16(cur, xrow, low0);
    float h = 0.0f;
    int low = low0;
    for (int i = 0; i < nsup; ++i) {
        int nlow = REV ? low - 16 : low + 16;
        int cln  = min(max(nlow, 0), T_LEN - 16);   // unconditional clamped prefetch
        float nxt[16];
        load16(nxt, xrow, cln);
        float o[16];
        #pragma unroll
        for (int jj = 0; jj < 16; ++jj) {
            int j = REV ? 15 - jj : jj;
            float xv = cur[j];
            h = gru_step(h, fmaf(xv, WR, CR), fmaf(xv, WZ, CZ), fmaf(xv, WN, CN),
                         UR, UZ, UN2, DN2);
            o[j] = h;
        }
        if (i >= warm_sup) store16(orow, low, o);   // wave-uniform branch
        #pragma unroll
        for (int k = 0; k < 16; ++k) cur[k] = nxt[k];
        low = nlow;
    }
}

// ------------- Layers 1/2: input [dir][b][t], two streams -------------
template<bool REV>
__device__ void scan_l12_dir(const float* __restrict__ in,
                             const float* __restrict__ wih, const float* __restrict__ whh,
                             const float* __restrict__ bih, const float* __restrict__ bhh,
                             float* __restrict__ out, int b, int s)
{
    const int d = REV ? 1 : 0;
    const float L2E = 1.4426950408889634f;
    const float WR0 = -L2E * wih[(d*3+0)*2+0], WR1 = -L2E * wih[(d*3+0)*2+1];
    const float WZ0 = -L2E * wih[(d*3+1)*2+0], WZ1 = -L2E * wih[(d*3+1)*2+1];
    const float WN0 =  2.0f*L2E * wih[(d*3+2)*2+0], WN1 = 2.0f*L2E * wih[(d*3+2)*2+1];
    const float UR  = -L2E * whh[d*3+0];
    const float UZ  = -L2E * whh[d*3+1];
    const float UN2 =  2.0f*L2E * whh[d*3+2];
    const float CR  = -L2E * (bih[d*3+0] + bhh[d*3+0]);
    const float CZ  = -L2E * (bih[d*3+1] + bhh[d*3+1]);
    const float CN  =  2.0f*L2E * bih[d*3+2];
    const float DN2 =  2.0f*L2E * bhh[d*3+2];

    int warm, low0;
    if (!REV) { warm = min(HALO, s * CL);               low0 = s * CL - warm; }
    else      { warm = min(HALO, T_LEN - (s + 1) * CL); low0 = (s + 1) * CL + warm - 16; }
    const int nsup = (warm + CL) >> 4;
    const int warm_sup = warm >> 4;

    const float* frow = in + (size_t)b * T_LEN;
    const float* grow = in + ((size_t)B_SZ + b) * T_LEN;
    float* orow = out + ((size_t)d * B_SZ + b) * T_LEN;

    float cf[16], cg[16];
    load16(cf, frow, low0);
    load16(cg, grow, low0);
    float h = 0.0f;
    int low = low0;
    for (int i = 0; i < nsup; ++i) {
        int nlow = REV ? low - 16 : low + 16;
        int cln  = min(max(nlow, 0), T_LEN - 16);
        float nf[16], ng[16];
        load16(nf, frow, cln);
        load16(ng, grow, cln);
        float o[16];
        #pragma unroll
        for (int jj = 0; jj < 16; ++jj) {
            int j = REV ? 15 - jj : jj;
            float a = cf[j], g2 = cg[j];
            float pr = fmaf(a, WR0, fmaf(g2, WR1, CR));
            float pz = fmaf(a, WZ0, fmaf(g2, WZ1, CZ));
            float pn = fmaf(a, WN0, fmaf(g2, WN1, CN));
            h = gru_step(h, pr, pz, pn, UR, UZ, UN2, DN2);
            o[j] = h;
        }
        if (i >= warm_sup) store16(orow, low, o);
        #pragma unroll
        for (int k = 0; k < 16; ++k) { cf[k] = nf[k]; cg[k] = ng[k]; }
        low = nlow;
    }
}

// Grid 2048 x 64: blockIdx bits [1:0]=batch group, [9:2]=chunk, [10]=direction.
__global__ void __launch_bounds__(64) k_scan_l0(const float* __restrict__ x,
                                                const float* __restrict__ wih,
                                                const float* __restrict__ whh,
                                                const float* __restrict__ bih,
                                                const float* __restrict__ bhh,
                                                float* __restrict__ out)
{
    int b = (blockIdx.x & 3) * 64 + threadIdx.x;
    int s = (blockIdx.x >> 2) & (S_CH - 1);
    if (blockIdx.x < 4 * S_CH) scan_l0_dir<false>(x, wih, whh, bih, bhh, out, b, s);
    else                       scan_l0_dir<true >(x, wih, whh, bih, bhh, out, b, s);
}

__global__ void __launch_bounds__(64) k_scan_l12(const float* __restrict__ in,
                                                 const float* __restrict__ wih,
                                                 const float* __restrict__ whh,
                                                 const float* __restrict__ bih,
                                                 const float* __restrict__ bhh,
                                                 float* __restrict__ out)
{
    int b = (blockIdx.x & 3) * 64 + threadIdx.x;
    int s = (blockIdx.x >> 2) & (S_CH - 1);
    if (blockIdx.x < 4 * S_CH) scan_l12_dir<false>(in, wih, whh, bih, bhh, out, b, s);
    else                       scan_l12_dir<true >(in, wih, whh, bih, bhh, out, b, s);
}

// y[b][0][t] = wf * h2[0][b][t] + wb * h2[1][b][t] + bias
__global__ void __launch_bounds__(256) k_proj(const float* __restrict__ h2,
                                              const float* __restrict__ wo,
                                              const float* __restrict__ bo,
                                              float* __restrict__ y)
{
    int gid = blockIdx.x * 256 + threadIdx.x;
    int b = gid / (T_LEN / 4), t4 = gid % (T_LEN / 4);
    const float wf = wo[0], wb = wo[1], bias = bo[0];
    float4 f = *(const float4*)(h2 + (size_t)b * T_LEN + 4 * t4);
    float4 g = *(const float4*)(h2 + ((size_t)B_SZ + b) * T_LEN + 4 * t4);
    float4 o;
    o.x = fmaf(wf, f.x, fmaf(wb, g.x, bias));
    o.y = fmaf(wf, f.y, fmaf(wb, g.y, bias));
    o.z = fmaf(wf, f.z, fmaf(wb, g.z, bias));
    o.w = fmaf(wf, f.w, fmaf(wb, g.w, bias));
    *(float4*)(y + (size_t)b * T_LEN + 4 * t4) = o;
}

extern "C" void kernel_launch(void* const* d_in, const int* in_sizes, int n_in,
                              void* d_out, int out_size, void* d_ws, size_t ws_size,
                              hipStream_t stream)
{
    (void)in_sizes; (void)n_in; (void)out_size; (void)ws_size;
    const float* x      = (const float*)d_in[0];
    const float* w_ih0  = (const float*)d_in[1];
    const float* w_hh0  = (const float*)d_in[2];
    const float* b_ih0  = (const float*)d_in[3];
    const float* b_hh0  = (const float*)d_in[4];
    const float* w_ih12 = (const float*)d_in[5];   // (2,2,3,2)
    const float* w_hh12 = (const float*)d_in[6];   // (2,2,3,1)
    const float* b_ih12 = (const float*)d_in[7];   // (2,2,3)
    const float* b_hh12 = (const float*)d_in[8];   // (2,2,3)
    const float* w_out  = (const float*)d_in[9];
    const float* b_out  = (const float*)d_in[10];
    float* y = (float*)d_out;

    float* buf0 = (float*)d_ws;                          // [2][B][T]
    float* buf1 = buf0 + (size_t)2 * B_SZ * T_LEN;       // [2][B][T]

    const int nblk = 8 * S_CH;   // 2 dirs x 4 batch-groups x S_CH chunks
    k_scan_l0 <<<nblk, 64, 0, stream>>>(x,    w_ih0,       w_hh0,      b_ih0,      b_hh0,      buf0);
    k_scan_l12<<<nblk, 64, 0, stream>>>(buf0, w_ih12 + 0,  w_hh12 + 0, b_ih12 + 0, b_hh12 + 0, buf1);
    k_scan_l12<<<nblk, 64, 0, stream>>>(buf1, w_ih12 + 12, w_hh12 + 6, b_ih12 + 6, b_hh12 + 6, buf0);
    k_proj    <<<4096, 256, 0, stream>>>(buf0, w_out, b_out, y);
}

// Round 4
// 180.258 us; speedup vs baseline: 29.5089x; 1.4936x over previous
//
#include <hip/hip_runtime.h>

#define T_LEN 16384
#define B_SZ  256
#define S_CH  256                // time chunks per direction
#define CL    (T_LEN / S_CH)     // 64 stored steps per chunk
#define HALO  128                // burn-in steps (contractive recurrence)

__device__ __forceinline__ float ex2(float x)  { return __builtin_amdgcn_exp2f(x); }
__device__ __forceinline__ float rcpf(float x) { return __builtin_amdgcn_rcpf(x); }

// One GRU step, H=1. UR,UZ pre-scaled by -log2e; UN2,DN2 by +2log2e.
__device__ __forceinline__ float gru_step(float h, float preR, float preZ, float preN,
                                          float UR, float UZ, float UN2, float DN2)
{
    float er  = ex2(fmaf(h, UR, preR));
    float ez  = ex2(fmaf(h, UZ, preZ));
    float r   = rcpf(1.0f + er);
    float z   = rcpf(1.0f + ez);
    float hn2 = fmaf(h, UN2, DN2);                    // off critical path
    float en  = ex2(fmaf(r, hn2, preN));
    float n   = fmaf(-2.0f, rcpf(1.0f + en), 1.0f);   // tanh via exp2
    float omz = 1.0f - z;
    float zh  = z * h;
    return fmaf(n, omz, zh);
}

// ---------- transpose x[b][t] -> xT[t][b] (LDS tiled, coalesced both sides) ----------
__global__ void __launch_bounds__(256) k_tr(const float* __restrict__ x, float* __restrict__ xT)
{
    __shared__ float tile[64][65];          // [t_local][b_local], pad breaks conflicts
    const int b0 = (blockIdx.x & 3) * 64;
    const int t0 = (blockIdx.x >> 2) * 64;
    const int c4 = threadIdx.x & 15;        // float4 index along fast dim
    const int r  = threadIdx.x >> 4;        // 0..15
    #pragma unroll
    for (int i = 0; i < 4; ++i) {
        int row = r + 16 * i;               // b_local
        float4 v = ((const float4*)x)[(size_t)(b0 + row) * (T_LEN / 4) + t0 / 4 + c4];
        tile[c4*4+0][row] = v.x; tile[c4*4+1][row] = v.y;
        tile[c4*4+2][row] = v.z; tile[c4*4+3][row] = v.w;
    }
    __syncthreads();
    #pragma unroll
    for (int i = 0; i < 4; ++i) {
        int trow = r + 16 * i;              // t_local
        float4 v = make_float4(tile[trow][c4*4+0], tile[trow][c4*4+1],
                               tile[trow][c4*4+2], tile[trow][c4*4+3]);
        ((float4*)xT)[(size_t)(t0 + trow) * (B_SZ / 4) + b0 / 4 + c4] = v;
    }
}

// ---------------- Layer 0 scan: xT[t][b] -> out[t][2][b] ----------------
template<bool REV>
__device__ void scan0(const float* __restrict__ xT,
                      const float* __restrict__ wih, const float* __restrict__ whh,
                      const float* __restrict__ bih, const float* __restrict__ bhh,
                      float* __restrict__ out, int b, int s)
{
    const int d = REV ? 1 : 0;
    const float L2E = 1.4426950408889634f;
    const float WR  = -L2E * wih[d*3+0];
    const float WZ  = -L2E * wih[d*3+1];
    const float WN  =  2.0f*L2E * wih[d*3+2];
    const float UR  = -L2E * whh[d*3+0];
    const float UZ  = -L2E * whh[d*3+1];
    const float UN2 =  2.0f*L2E * whh[d*3+2];
    const float CR  = -L2E * (bih[d*3+0] + bhh[d*3+0]);
    const float CZ  = -L2E * (bih[d*3+1] + bhh[d*3+1]);
    const float CN  =  2.0f*L2E * bih[d*3+2];
    const float DN2 =  2.0f*L2E * bhh[d*3+2];

    const int warm   = min(HALO, REV ? (T_LEN - (s + 1) * CL) : (s * CL));
    const int nsteps = warm + CL;           // {64,128,192}: nsup always even
    const int t0     = REV ? ((s + 1) * CL - 1 + warm) : (s * CL - warm);

    const float* px = xT + b;
    float* po = out + (REV ? B_SZ : 0) + b;

    float xA[16], xB[16];
    float h = 0.0f;

#define LD0(F, base_) { int base = (base_); \
    _Pragma("unroll") for (int k = 0; k < 16; ++k) { \
      int t = REV ? (t0 - (base + k)) : (t0 + (base + k)); \
      F[k] = px[t * B_SZ]; } \
    __builtin_amdgcn_sched_barrier(0); }

#define CS0(F, base_) { int base = (base_); float ov[16]; \
    _Pragma("unroll") for (int k = 0; k < 16; ++k) { \
      float xv = F[k]; \
      h = gru_step(h, fmaf(xv, WR, CR), fmaf(xv, WZ, CZ), fmaf(xv, WN, CN), \
                   UR, UZ, UN2, DN2); ov[k] = h; } \
    if (base >= warm) { \
      _Pragma("unroll") for (int k = 0; k < 16; ++k) { \
        int t = REV ? (t0 - (base + k)) : (t0 + (base + k)); \
        po[t * (2 * B_SZ)] = ov[k]; } } }

    LD0(xA, 0);
    const int nsup = nsteps >> 4;
    for (int i = 0; i < nsup; i += 2) {
        LD0(xB, min((i + 1) * 16, nsteps - 16));
        CS0(xA, i * 16);
        LD0(xA, min((i + 2) * 16, nsteps - 16));
        CS0(xB, (i + 1) * 16);
    }
#undef LD0
#undef CS0
}

// ------------- Layers 1/2 scan: in[t][2][b] -> out[t][2][b] -------------
template<bool REV>
__device__ void scan12(const float* __restrict__ in,
                       const float* __restrict__ wih, const float* __restrict__ whh,
                       const float* __restrict__ bih, const float* __restrict__ bhh,
                       float* __restrict__ out, int b, int s)
{
    const int d = REV ? 1 : 0;
    const float L2E = 1.4426950408889634f;
    const float WR0 = -L2E * wih[(d*3+0)*2+0], WR1 = -L2E * wih[(d*3+0)*2+1];
    const float WZ0 = -L2E * wih[(d*3+1)*2+0], WZ1 = -L2E * wih[(d*3+1)*2+1];
    const float WN0 =  2.0f*L2E * wih[(d*3+2)*2+0], WN1 = 2.0f*L2E * wih[(d*3+2)*2+1];
    const float UR  = -L2E * whh[d*3+0];
    const float UZ  = -L2E * whh[d*3+1];
    const float UN2 =  2.0f*L2E * whh[d*3+2];
    const float CR  = -L2E * (bih[d*3+0] + bhh[d*3+0]);
    const float CZ  = -L2E * (bih[d*3+1] + bhh[d*3+1]);
    const float CN  =  2.0f*L2E * bih[d*3+2];
    const float DN2 =  2.0f*L2E * bhh[d*3+2];

    const int warm   = min(HALO, REV ? (T_LEN - (s + 1) * CL) : (s * CL));
    const int nsteps = warm + CL;
    const int t0     = REV ? ((s + 1) * CL - 1 + warm) : (s * CL - warm);

    const float* pf = in + b;
    const float* pg = in + B_SZ + b;
    float* po = out + (REV ? B_SZ : 0) + b;

    float fA[16], gA[16], fB[16], gB[16];
    float h = 0.0f;

#define LD12(F, G, base_) { int base = (base_); \
    _Pragma("unroll") for (int k = 0; k < 16; ++k) { \
      int t = REV ? (t0 - (base + k)) : (t0 + (base + k)); \
      F[k] = pf[t * (2 * B_SZ)]; G[k] = pg[t * (2 * B_SZ)]; } \
    __builtin_amdgcn_sched_barrier(0); }

#define CS12(F, G, base_) { int base = (base_); float ov[16]; \
    _Pragma("unroll") for (int k = 0; k < 16; ++k) { \
      float a = F[k], c = G[k]; \
      float pr = fmaf(a, WR0, fmaf(c, WR1, CR)); \
      float pz = fmaf(a, WZ0, fmaf(c, WZ1, CZ)); \
      float pn = fmaf(a, WN0, fmaf(c, WN1, CN)); \
      h = gru_step(h, pr, pz, pn, UR, UZ, UN2, DN2); ov[k] = h; } \
    if (base >= warm) { \
      _Pragma("unroll") for (int k = 0; k < 16; ++k) { \
        int t = REV ? (t0 - (base + k)) : (t0 + (base + k)); \
        po[t * (2 * B_SZ)] = ov[k]; } } }

    LD12(fA, gA, 0);
    const int nsup = nsteps >> 4;
    for (int i = 0; i < nsup; i += 2) {
        LD12(fB, gB, min((i + 1) * 16, nsteps - 16));
        CS12(fA, gA, i * 16);
        LD12(fA, gA, min((i + 2) * 16, nsteps - 16));
        CS12(fB, gB, (i + 1) * 16);
    }
#undef LD12
#undef CS12
}

// Grid 2048 x 64: bits [1:0]=batch group, [9:2]=chunk, [10]=direction.
__global__ void __launch_bounds__(64) k_scan0g(const float* __restrict__ xT,
                                               const float* __restrict__ wih,
                                               const float* __restrict__ whh,
                                               const float* __restrict__ bih,
                                               const float* __restrict__ bhh,
                                               float* __restrict__ out)
{
    int b = (blockIdx.x & 3) * 64 + threadIdx.x;
    int s = (blockIdx.x >> 2) & (S_CH - 1);
    if (blockIdx.x < 4 * S_CH) scan0<false>(xT, wih, whh, bih, bhh, out, b, s);
    else                       scan0<true >(xT, wih, whh, bih, bhh, out, b, s);
}

__global__ void __launch_bounds__(64) k_scan12g(const float* __restrict__ in,
                                                const float* __restrict__ wih,
                                                const float* __restrict__ whh,
                                                const float* __restrict__ bih,
                                                const float* __restrict__ bhh,
                                                float* __restrict__ out)
{
    int b = (blockIdx.x & 3) * 64 + threadIdx.x;
    int s = (blockIdx.x >> 2) & (S_CH - 1);
    if (blockIdx.x < 4 * S_CH) scan12<false>(in, wih, whh, bih, bhh, out, b, s);
    else                       scan12<true >(in, wih, whh, bih, bhh, out, b, s);
}

// proj + transpose back: y[b][t] = wf*h2[t][0][b] + wb*h2[t][1][b] + bias
__global__ void __launch_bounds__(256) k_proj(const float* __restrict__ h2,
                                              const float* __restrict__ wo,
                                              const float* __restrict__ bo,
                                              float* __restrict__ y)
{
    __shared__ float tile[64][65];          // [b_local][t_local]
    const int b0 = (blockIdx.x & 3) * 64;
    const int t0 = (blockIdx.x >> 2) * 64;
    const float wf = wo[0], wb = wo[1], bias = bo[0];
    const int bl = threadIdx.x & 63;
    const int tg = threadIdx.x >> 6;        // 0..3
    #pragma unroll
    for (int i = 0; i < 16; ++i) {
        int tl = tg * 16 + i;
        int t  = t0 + tl;
        float f = h2[t * (2 * B_SZ) + b0 + bl];
        float g = h2[t * (2 * B_SZ) + B_SZ + b0 + bl];
        tile[bl][tl] = fmaf(wf, f, fmaf(wb, g, bias));
    }
    __syncthreads();
    const int c4 = threadIdx.x & 15;
    const int r  = threadIdx.x >> 4;
    #pragma unroll
    for (int i = 0; i < 4; ++i) {
        int brow = r + 16 * i;
        float4 v = make_float4(tile[brow][c4*4+0], tile[brow][c4*4+1],
                               tile[brow][c4*4+2], tile[brow][c4*4+3]);
        ((float4*)y)[(size_t)(b0 + brow) * (T_LEN / 4) + t0 / 4 + c4] = v;
    }
}

extern "C" void kernel_launch(void* const* d_in, const int* in_sizes, int n_in,
                              void* d_out, int out_size, void* d_ws, size_t ws_size,
                              hipStream_t stream)
{
    (void)in_sizes; (void)n_in; (void)out_size; (void)ws_size;
    const float* x      = (const float*)d_in[0];
    const float* w_ih0  = (const float*)d_in[1];
    const float* w_hh0  = (const float*)d_in[2];
    const float* b_ih0  = (const float*)d_in[3];
    const float* b_hh0  = (const float*)d_in[4];
    const float* w_ih12 = (const float*)d_in[5];
    const float* w_hh12 = (const float*)d_in[6];
    const float* b_ih12 = (const float*)d_in[7];
    const float* b_hh12 = (const float*)d_in[8];
    const float* w_out  = (const float*)d_in[9];
    const float* b_out  = (const float*)d_in[10];
    float* y = (float*)d_out;

    // ws budget 67.1 MB (same as R1-R3):
    //   xT    at [0, 16.8MB)          — dead after layer 0
    //   l0out at [33.5, 67.1MB)
    //   l1out at [0, 33.5MB)          — overlays dead xT
    //   l2out at [33.5, 67.1MB)       — overlays dead l0out
    float* ws    = (float*)d_ws;
    float* xT    = ws;
    float* l0out = ws + (size_t)2 * B_SZ * T_LEN;
    float* l1out = ws;
    float* l2out = ws + (size_t)2 * B_SZ * T_LEN;

    const int nblk = 8 * S_CH;   // 2048
    k_tr     <<<1024, 256, 0, stream>>>(x, xT);
    k_scan0g <<<nblk, 64, 0, stream>>>(xT,    w_ih0,       w_hh0,      b_ih0,      b_hh0,      l0out);
    k_scan12g<<<nblk, 64, 0, stream>>>(l0out, w_ih12 + 0,  w_hh12 + 0, b_ih12 + 0, b_hh12 + 0, l1out);
    k_scan12g<<<nblk, 64, 0, stream>>>(l1out, w_ih12 + 12, w_hh12 + 6, b_ih12 + 6, b_hh12 + 6, l2out);
    k_proj   <<<1024, 256, 0, stream>>>(l2out, w_out, b_out, y);
}

// Round 5
// 171.143 us; speedup vs baseline: 31.0805x; 1.0533x over previous
//
#include <hip/hip_runtime.h>

#define T_LEN 16384
#define B_SZ  256
#define S_CH  256                // time chunks per direction
#define CL    (T_LEN / S_CH)     // 64 stored steps per chunk
#define HALO  64                 // burn-in steps (contractive recurrence)

__device__ __forceinline__ float ex2(float x)  { return __builtin_amdgcn_exp2f(x); }
__device__ __forceinline__ float rcpf(float x) { return __builtin_amdgcn_rcpf(x); }

// One GRU step, H=1. UR,UZ pre-scaled by -log2e; UN2,DN2 by +2log2e.
__device__ __forceinline__ float gru_step(float h, float preR, float preZ, float preN,
                                          float UR, float UZ, float UN2, float DN2)
{
    float er  = ex2(fmaf(h, UR, preR));
    float ez  = ex2(fmaf(h, UZ, preZ));
    float r   = rcpf(1.0f + er);
    float z   = rcpf(1.0f + ez);
    float hn2 = fmaf(h, UN2, DN2);                    // off critical path
    float en  = ex2(fmaf(r, hn2, preN));
    float n   = fmaf(-2.0f, rcpf(1.0f + en), 1.0f);   // tanh via exp2
    float omz = 1.0f - z;
    float zh  = z * h;
    return fmaf(n, omz, zh);
}

// ---------- transpose x[b][t] -> xT[t][b] (LDS tiled, coalesced both sides) ----------
__global__ void __launch_bounds__(256) k_tr(const float* __restrict__ x, float* __restrict__ xT)
{
    __shared__ float tile[64][65];
    const int b0 = (blockIdx.x & 3) * 64;
    const int t0 = (blockIdx.x >> 2) * 64;
    const int c4 = threadIdx.x & 15;
    const int r  = threadIdx.x >> 4;
    #pragma unroll
    for (int i = 0; i < 4; ++i) {
        int row = r + 16 * i;               // b_local
        float4 v = ((const float4*)x)[(size_t)(b0 + row) * (T_LEN / 4) + t0 / 4 + c4];
        tile[c4*4+0][row] = v.x; tile[c4*4+1][row] = v.y;
        tile[c4*4+2][row] = v.z; tile[c4*4+3][row] = v.w;
    }
    __syncthreads();
    #pragma unroll
    for (int i = 0; i < 4; ++i) {
        int trow = r + 16 * i;              // t_local
        float4 v = make_float4(tile[trow][c4*4+0], tile[trow][c4*4+1],
                               tile[trow][c4*4+2], tile[trow][c4*4+3]);
        ((float4*)xT)[(size_t)(t0 + trow) * (B_SZ / 4) + b0 / 4 + c4] = v;
    }
}

// ---------------- Layer 0 scan: xT[t][b] -> out[t][b][2] ----------------
template<bool REV>
__device__ void scan0(const float* __restrict__ xT,
                      const float* __restrict__ wih, const float* __restrict__ whh,
                      const float* __restrict__ bih, const float* __restrict__ bhh,
                      float* __restrict__ out, int b, int s)
{
    const int d = REV ? 1 : 0;
    const float L2E = 1.4426950408889634f;
    const float WR  = -L2E * wih[d*3+0];
    const float WZ  = -L2E * wih[d*3+1];
    const float WN  =  2.0f*L2E * wih[d*3+2];
    const float UR  = -L2E * whh[d*3+0];
    const float UZ  = -L2E * whh[d*3+1];
    const float UN2 =  2.0f*L2E * whh[d*3+2];
    const float CR  = -L2E * (bih[d*3+0] + bhh[d*3+0]);
    const float CZ  = -L2E * (bih[d*3+1] + bhh[d*3+1]);
    const float CN  =  2.0f*L2E * bih[d*3+2];
    const float DN2 =  2.0f*L2E * bhh[d*3+2];

    const int warm   = min(HALO, REV ? (T_LEN - (s + 1) * CL) : (s * CL));
    const int nsteps = warm + CL;           // nsup in {4,8}: always even
    const int t0     = REV ? ((s + 1) * CL - 1 + warm) : (s * CL - warm);

    const float* px = xT + b;
    float* po = out + 2 * b + d;            // [t][b][2]

    float xA[16], xB[16];
    float h = 0.0f;

#define LD0(F, base_) { int base = (base_); \
    _Pragma("unroll") for (int k = 0; k < 16; ++k) { \
      int t = REV ? (t0 - (base + k)) : (t0 + (base + k)); \
      F[k] = px[t * B_SZ]; } \
    __builtin_amdgcn_sched_barrier(0); }

#define CS0(F, base_) { int base = (base_); float ov[16]; \
    _Pragma("unroll") for (int k = 0; k < 16; ++k) { \
      float xv = F[k]; \
      h = gru_step(h, fmaf(xv, WR, CR), fmaf(xv, WZ, CZ), fmaf(xv, WN, CN), \
                   UR, UZ, UN2, DN2); ov[k] = h; } \
    if (base >= warm) { \
      _Pragma("unroll") for (int k = 0; k < 16; ++k) { \
        int t = REV ? (t0 - (base + k)) : (t0 + (base + k)); \
        po[t * (2 * B_SZ)] = ov[k]; } } }

    LD0(xA, 0);
    const int nsup = nsteps >> 4;
    for (int i = 0; i < nsup; i += 2) {
        LD0(xB, min((i + 1) * 16, nsteps - 16));
        CS0(xA, i * 16);
        LD0(xA, min((i + 2) * 16, nsteps - 16));
        CS0(xB, (i + 1) * 16);
    }
#undef LD0
#undef CS0
}

// ------------- Layers 1/2 scan: in[t][b][2] -> out[t][b][2] -------------
template<bool REV>
__device__ void scan12(const float* __restrict__ in,
                       const float* __restrict__ wih, const float* __restrict__ whh,
                       const float* __restrict__ bih, const float* __restrict__ bhh,
                       float* __restrict__ out, int b, int s)
{
    const int d = REV ? 1 : 0;
    const float L2E = 1.4426950408889634f;
    const float WR0 = -L2E * wih[(d*3+0)*2+0], WR1 = -L2E * wih[(d*3+0)*2+1];
    const float WZ0 = -L2E * wih[(d*3+1)*2+0], WZ1 = -L2E * wih[(d*3+1)*2+1];
    const float WN0 =  2.0f*L2E * wih[(d*3+2)*2+0], WN1 = 2.0f*L2E * wih[(d*3+2)*2+1];
    const float UR  = -L2E * whh[d*3+0];
    const float UZ  = -L2E * whh[d*3+1];
    const float UN2 =  2.0f*L2E * whh[d*3+2];
    const float CR  = -L2E * (bih[d*3+0] + bhh[d*3+0]);
    const float CZ  = -L2E * (bih[d*3+1] + bhh[d*3+1]);
    const float CN  =  2.0f*L2E * bih[d*3+2];
    const float DN2 =  2.0f*L2E * bhh[d*3+2];

    const int warm   = min(HALO, REV ? (T_LEN - (s + 1) * CL) : (s * CL));
    const int nsteps = warm + CL;
    const int t0     = REV ? ((s + 1) * CL - 1 + warm) : (s * CL - warm);

    const float2* pin = (const float2*)in + b;   // [t][b] of float2
    float* po = out + 2 * b + d;

    float2 vA[16], vB[16];
    float h = 0.0f;

#define LD12(V, base_) { int base = (base_); \
    _Pragma("unroll") for (int k = 0; k < 16; ++k) { \
      int t = REV ? (t0 - (base + k)) : (t0 + (base + k)); \
      V[k] = pin[t * B_SZ]; } \
    __builtin_amdgcn_sched_barrier(0); }

#define CS12(V, base_) { int base = (base_); float ov[16]; \
    _Pragma("unroll") for (int k = 0; k < 16; ++k) { \
      float a = V[k].x, c = V[k].y; \
      float pr = fmaf(a, WR0, fmaf(c, WR1, CR)); \
      float pz = fmaf(a, WZ0, fmaf(c, WZ1, CZ)); \
      float pn = fmaf(a, WN0, fmaf(c, WN1, CN)); \
      h = gru_step(h, pr, pz, pn, UR, UZ, UN2, DN2); ov[k] = h; } \
    if (base >= warm) { \
      _Pragma("unroll") for (int k = 0; k < 16; ++k) { \
        int t = REV ? (t0 - (base + k)) : (t0 + (base + k)); \
        po[t * (2 * B_SZ)] = ov[k]; } } }

    LD12(vA, 0);
    const int nsup = nsteps >> 4;
    for (int i = 0; i < nsup; i += 2) {
        LD12(vB, min((i + 1) * 16, nsteps - 16));
        CS12(vA, i * 16);
        LD12(vA, min((i + 2) * 16, nsteps - 16));
        CS12(vB, (i + 1) * 16);
    }
#undef LD12
#undef CS12
}

// 2048 blocks. XCD-aware swizzle (heuristic, correctness-independent):
// xcd = blk&7 owns chunks [xcd*32, xcd*32+32) for both dirs & all batch groups,
// so halo overlap between neighboring chunks stays in that XCD's 4MB L2.
__device__ __forceinline__ void decode_blk(int blk, int tid, int& b, int& s, int& dir)
{
    int xcd = blk & 7;
    int j   = blk >> 3;            // 0..255
    int sl  = j & 31;
    int bg  = (j >> 5) & 3;
    dir     = j >> 7;
    s       = xcd * 32 + sl;
    b       = bg * 64 + tid;
}

__global__ void __launch_bounds__(64) k_scan0g(const float* __restrict__ xT,
                                               const float* __restrict__ wih,
                                               const float* __restrict__ whh,
                                               const float* __restrict__ bih,
                                               const float* __restrict__ bhh,
                                               float* __restrict__ out)
{
    int b, s, dir;
    decode_blk(blockIdx.x, threadIdx.x, b, s, dir);
    if (dir == 0) scan0<false>(xT, wih, whh, bih, bhh, out, b, s);
    else          scan0<true >(xT, wih, whh, bih, bhh, out, b, s);
}

__global__ void __launch_bounds__(64) k_scan12g(const float* __restrict__ in,
                                                const float* __restrict__ wih,
                                                const float* __restrict__ whh,
                                                const float* __restrict__ bih,
                                                const float* __restrict__ bhh,
                                                float* __restrict__ out)
{
    int b, s, dir;
    decode_blk(blockIdx.x, threadIdx.x, b, s, dir);
    if (dir == 0) scan12<false>(in, wih, whh, bih, bhh, out, b, s);
    else          scan12<true >(in, wih, whh, bih, bhh, out, b, s);
}

// proj + transpose back: y[b][t] = wf*h2[t][b].x + wb*h2[t][b].y + bias
__global__ void __launch_bounds__(256) k_proj(const float* __restrict__ h2,
                                              const float* __restrict__ wo,
                                              const float* __restrict__ bo,
                                              float* __restrict__ y)
{
    __shared__ float tile[64][65];          // [b_local][t_local]
    const int b0 = (blockIdx.x & 3) * 64;
    const int t0 = (blockIdx.x >> 2) * 64;
    const float wf = wo[0], wb = wo[1], bias = bo[0];
    const int bl = threadIdx.x & 63;
    const int tg = threadIdx.x >> 6;        // 0..3
    const float2* h2p = (const float2*)h2;
    #pragma unroll
    for (int i = 0; i < 16; ++i) {
        int tl = tg * 16 + i;
        int t  = t0 + tl;
        float2 c = h2p[(size_t)t * B_SZ + b0 + bl];
        tile[bl][tl] = fmaf(wf, c.x, fmaf(wb, c.y, bias));
    }
    __syncthreads();
    const int c4 = threadIdx.x & 15;
    const int r  = threadIdx.x >> 4;
    #pragma unroll
    for (int i = 0; i < 4; ++i) {
        int brow = r + 16 * i;
        float4 v = make_float4(tile[brow][c4*4+0], tile[brow][c4*4+1],
                               tile[brow][c4*4+2], tile[brow][c4*4+3]);
        ((float4*)y)[(size_t)(b0 + brow) * (T_LEN / 4) + t0 / 4 + c4] = v;
    }
}

extern "C" void kernel_launch(void* const* d_in, const int* in_sizes, int n_in,
                              void* d_out, int out_size, void* d_ws, size_t ws_size,
                              hipStream_t stream)
{
    (void)in_sizes; (void)n_in; (void)out_size; (void)ws_size;
    const float* x      = (const float*)d_in[0];
    const float* w_ih0  = (const float*)d_in[1];
    const float* w_hh0  = (const float*)d_in[2];
    const float* b_ih0  = (const float*)d_in[3];
    const float* b_hh0  = (const float*)d_in[4];
    const float* w_ih12 = (const float*)d_in[5];
    const float* w_hh12 = (const float*)d_in[6];
    const float* b_ih12 = (const float*)d_in[7];
    const float* b_hh12 = (const float*)d_in[8];
    const float* w_out  = (const float*)d_in[9];
    const float* b_out  = (const float*)d_in[10];
    float* y = (float*)d_out;

    // ws: xT [0,16.8MB) dead after layer0; l0out [33.5,67.1); l1out overlays xT
    // region [0,33.5); l2out overlays l0out [33.5,67.1).
    float* ws    = (float*)d_ws;
    float* xT    = ws;
    float* l0out = ws + (size_t)2 * B_SZ * T_LEN;
    float* l1out = ws;
    float* l2out = ws + (size_t)2 * B_SZ * T_LEN;

    const int nblk = 8 * S_CH;   // 2048
    k_tr     <<<1024, 256, 0, stream>>>(x, xT);
    k_scan0g <<<nblk, 64, 0, stream>>>(xT,    w_ih0,       w_hh0,      b_ih0,      b_hh0,      l0out);
    k_scan12g<<<nblk, 64, 0, stream>>>(l0out, w_ih12 + 0,  w_hh12 + 0, b_ih12 + 0, b_hh12 + 0, l1out);
    k_scan12g<<<nblk, 64, 0, stream>>>(l1out, w_ih12 + 12, w_hh12 + 6, b_ih12 + 6, b_hh12 + 6, l2out);
    k_proj   <<<1024, 256, 0, stream>>>(l2out, w_out, b_out, y);
}

// Round 6
// 157.826 us; speedup vs baseline: 33.7032x; 1.0844x over previous
//
#include <hip/hip_runtime.h>

#define T_LEN 16384
#define B_SZ  256
#define S_CH  256                // time chunks per direction
#define CL    (T_LEN / S_CH)     // 64 stored steps per chunk
#define HALO  64                 // burn-in steps (contractive recurrence)

__device__ __forceinline__ float ex2(float x)  { return __builtin_amdgcn_exp2f(x); }
__device__ __forceinline__ float rcpf(float x) { return __builtin_amdgcn_rcpf(x); }

// One GRU step, H=1. UR,UZ pre-scaled by -log2e; UN2,DN2 by +2log2e.
__device__ __forceinline__ float gru_step(float h, float preR, float preZ, float preN,
                                          float UR, float UZ, float UN2, float DN2)
{
    float er  = ex2(fmaf(h, UR, preR));
    float ez  = ex2(fmaf(h, UZ, preZ));
    float r   = rcpf(1.0f + er);
    float z   = rcpf(1.0f + ez);
    float hn2 = fmaf(h, UN2, DN2);                    // off critical path
    float en  = ex2(fmaf(r, hn2, preN));
    float n   = fmaf(-2.0f, rcpf(1.0f + en), 1.0f);   // tanh via exp2
    float omz = 1.0f - z;
    float zh  = z * h;
    return fmaf(n, omz, zh);
}

// ---------- transpose x[b][t] -> xT[t][b] (LDS tiled, coalesced both sides) ----------
__global__ void __launch_bounds__(256) k_tr(const float* __restrict__ x, float* __restrict__ xT)
{
    __shared__ float tile[64][65];
    const int b0 = (blockIdx.x & 3) * 64;
    const int t0 = (blockIdx.x >> 2) * 64;
    const int c4 = threadIdx.x & 15;
    const int r  = threadIdx.x >> 4;
    #pragma unroll
    for (int i = 0; i < 4; ++i) {
        int row = r + 16 * i;               // b_local
        float4 v = ((const float4*)x)[(size_t)(b0 + row) * (T_LEN / 4) + t0 / 4 + c4];
        tile[c4*4+0][row] = v.x; tile[c4*4+1][row] = v.y;
        tile[c4*4+2][row] = v.z; tile[c4*4+3][row] = v.w;
    }
    __syncthreads();
    #pragma unroll
    for (int i = 0; i < 4; ++i) {
        int trow = r + 16 * i;              // t_local
        float4 v = make_float4(tile[trow][c4*4+0], tile[trow][c4*4+1],
                               tile[trow][c4*4+2], tile[trow][c4*4+3]);
        ((float4*)xT)[(size_t)(t0 + trow) * (B_SZ / 4) + b0 / 4 + c4] = v;
    }
}

// ---------------- Layer 0 scan: xT[t][b] -> out[t][2][b] ----------------
// Dense stores: 64 lanes write 256B contiguous per t (no partial lines).
template<bool REV>
__device__ void scan0(const float* __restrict__ xT,
                      const float* __restrict__ wih, const float* __restrict__ whh,
                      const float* __restrict__ bih, const float* __restrict__ bhh,
                      float* __restrict__ out, int b, int s)
{
    const int d = REV ? 1 : 0;
    const float L2E = 1.4426950408889634f;
    const float WR  = -L2E * wih[d*3+0];
    const float WZ  = -L2E * wih[d*3+1];
    const float WN  =  2.0f*L2E * wih[d*3+2];
    const float UR  = -L2E * whh[d*3+0];
    const float UZ  = -L2E * whh[d*3+1];
    const float UN2 =  2.0f*L2E * whh[d*3+2];
    const float CR  = -L2E * (bih[d*3+0] + bhh[d*3+0]);
    const float CZ  = -L2E * (bih[d*3+1] + bhh[d*3+1]);
    const float CN  =  2.0f*L2E * bih[d*3+2];
    const float DN2 =  2.0f*L2E * bhh[d*3+2];

    const int warm   = min(HALO, REV ? (T_LEN - (s + 1) * CL) : (s * CL));
    const int nsteps = warm + CL;           // nsup in {4,8}: always even
    const int t0     = REV ? ((s + 1) * CL - 1 + warm) : (s * CL - warm);

    const float* px = xT + b;
    float* po = out + (REV ? B_SZ : 0) + b;   // [t][2][b]

    float xA[16], xB[16];
    float h = 0.0f;

#define LD0(F, base_) { int base = (base_); \
    _Pragma("unroll") for (int k = 0; k < 16; ++k) { \
      int t = REV ? (t0 - (base + k)) : (t0 + (base + k)); \
      F[k] = px[t * B_SZ]; } \
    __builtin_amdgcn_sched_barrier(0); }

#define CS0(F, base_) { int base = (base_); float ov[16]; \
    _Pragma("unroll") for (int k = 0; k < 16; ++k) { \
      float xv = F[k]; \
      h = gru_step(h, fmaf(xv, WR, CR), fmaf(xv, WZ, CZ), fmaf(xv, WN, CN), \
                   UR, UZ, UN2, DN2); ov[k] = h; } \
    if (base >= warm) { \
      _Pragma("unroll") for (int k = 0; k < 16; ++k) { \
        int t = REV ? (t0 - (base + k)) : (t0 + (base + k)); \
        po[t * (2 * B_SZ)] = ov[k]; } } }

    LD0(xA, 0);
    const int nsup = nsteps >> 4;
    for (int i = 0; i < nsup; i += 2) {
        LD0(xB, min((i + 1) * 16, nsteps - 16));
        CS0(xA, i * 16);
        LD0(xA, min((i + 2) * 16, nsteps - 16));
        CS0(xB, (i + 1) * 16);
    }
#undef LD0
#undef CS0
}

// ------------- Layers 1/2 scan: in[t][2][b] -> out[t][2][b] -------------
template<bool REV>
__device__ void scan12(const float* __restrict__ in,
                       const float* __restrict__ wih, const float* __restrict__ whh,
                       const float* __restrict__ bih, const float* __restrict__ bhh,
                       float* __restrict__ out, int b, int s)
{
    const int d = REV ? 1 : 0;
    const float L2E = 1.4426950408889634f;
    const float WR0 = -L2E * wih[(d*3+0)*2+0], WR1 = -L2E * wih[(d*3+0)*2+1];
    const float WZ0 = -L2E * wih[(d*3+1)*2+0], WZ1 = -L2E * wih[(d*3+1)*2+1];
    const float WN0 =  2.0f*L2E * wih[(d*3+2)*2+0], WN1 = 2.0f*L2E * wih[(d*3+2)*2+1];
    const float UR  = -L2E * whh[d*3+0];
    const float UZ  = -L2E * whh[d*3+1];
    const float UN2 =  2.0f*L2E * whh[d*3+2];
    const float CR  = -L2E * (bih[d*3+0] + bhh[d*3+0]);
    const float CZ  = -L2E * (bih[d*3+1] + bhh[d*3+1]);
    const float CN  =  2.0f*L2E * bih[d*3+2];
    const float DN2 =  2.0f*L2E * bhh[d*3+2];

    const int warm   = min(HALO, REV ? (T_LEN - (s + 1) * CL) : (s * CL));
    const int nsteps = warm + CL;
    const int t0     = REV ? ((s + 1) * CL - 1 + warm) : (s * CL - warm);

    const float* pf = in + b;                 // fwd stream
    const float* pg = in + B_SZ + b;          // bwd stream
    float* po = out + (REV ? B_SZ : 0) + b;

    float fA[16], gA[16], fB[16], gB[16];
    float h = 0.0f;

#define LD12(F, G, base_) { int base = (base_); \
    _Pragma("unroll") for (int k = 0; k < 16; ++k) { \
      int t = REV ? (t0 - (base + k)) : (t0 + (base + k)); \
      F[k] = pf[t * (2 * B_SZ)]; G[k] = pg[t * (2 * B_SZ)]; } \
    __builtin_amdgcn_sched_barrier(0); }

#define CS12(F, G, base_) { int base = (base_); float ov[16]; \
    _Pragma("unroll") for (int k = 0; k < 16; ++k) { \
      float a = F[k], c = G[k]; \
      float pr = fmaf(a, WR0, fmaf(c, WR1, CR)); \
      float pz = fmaf(a, WZ0, fmaf(c, WZ1, CZ)); \
      float pn = fmaf(a, WN0, fmaf(c, WN1, CN)); \
      h = gru_step(h, pr, pz, pn, UR, UZ, UN2, DN2); ov[k] = h; } \
    if (base >= warm) { \
      _Pragma("unroll") for (int k = 0; k < 16; ++k) { \
        int t = REV ? (t0 - (base + k)) : (t0 + (base + k)); \
        po[t * (2 * B_SZ)] = ov[k]; } } }

    LD12(fA, gA, 0);
    const int nsup = nsteps >> 4;
    for (int i = 0; i < nsup; i += 2) {
        LD12(fB, gB, min((i + 1) * 16, nsteps - 16));
        CS12(fA, gA, i * 16);
        LD12(fA, gA, min((i + 2) * 16, nsteps - 16));
        CS12(fB, gB, (i + 1) * 16);
    }
#undef LD12
#undef CS12
}

// 2048 blocks. XCD swizzle: xcd = blk&7 owns chunks [xcd*32, xcd*32+32) for
// both dirs & all batch groups -> halo re-reads stay in that XCD's 4MB L2.
__device__ __forceinline__ void decode_blk(int blk, int tid, int& b, int& s, int& dir)
{
    int xcd = blk & 7;
    int j   = blk >> 3;            // 0..255
    int sl  = j & 31;
    int bg  = (j >> 5) & 3;
    dir     = j >> 7;
    s       = xcd * 32 + sl;
    b       = bg * 64 + tid;
}

__global__ void __launch_bounds__(64) k_scan0g(const float* __restrict__ xT,
                                               const float* __restrict__ wih,
                                               const float* __restrict__ whh,
                                               const float* __restrict__ bih,
                                               const float* __restrict__ bhh,
                                               float* __restrict__ out)
{
    int b, s, dir;
    decode_blk(blockIdx.x, threadIdx.x, b, s, dir);
    if (dir == 0) scan0<false>(xT, wih, whh, bih, bhh, out, b, s);
    else          scan0<true >(xT, wih, whh, bih, bhh, out, b, s);
}

__global__ void __launch_bounds__(64) k_scan12g(const float* __restrict__ in,
                                                const float* __restrict__ wih,
                                                const float* __restrict__ whh,
                                                const float* __restrict__ bih,
                                                const float* __restrict__ bhh,
                                                float* __restrict__ out)
{
    int b, s, dir;
    decode_blk(blockIdx.x, threadIdx.x, b, s, dir);
    if (dir == 0) scan12<false>(in, wih, whh, bih, bhh, out, b, s);
    else          scan12<true >(in, wih, whh, bih, bhh, out, b, s);
}

// proj + transpose back: y[b][t] = wf*h2[t][0][b] + wb*h2[t][1][b] + bias
__global__ void __launch_bounds__(256) k_proj(const float* __restrict__ h2,
                                              const float* __restrict__ wo,
                                              const float* __restrict__ bo,
                                              float* __restrict__ y)
{
    __shared__ float tile[64][65];          // [b_local][t_local]
    const int b0 = (blockIdx.x & 3) * 64;
    const int t0 = (blockIdx.x >> 2) * 64;
    const float wf = wo[0], wb = wo[1], bias = bo[0];
    const int bl = threadIdx.x & 63;
    const int tg = threadIdx.x >> 6;        // 0..3
    #pragma unroll
    for (int i = 0; i < 16; ++i) {
        int tl = tg * 16 + i;
        int t  = t0 + tl;
        float f = h2[(size_t)t * (2 * B_SZ) + b0 + bl];
        float g = h2[(size_t)t * (2 * B_SZ) + B_SZ + b0 + bl];
        tile[bl][tl] = fmaf(wf, f, fmaf(wb, g, bias));
    }
    __syncthreads();
    const int c4 = threadIdx.x & 15;
    const int r  = threadIdx.x >> 4;
    #pragma unroll
    for (int i = 0; i < 4; ++i) {
        int brow = r + 16 * i;
        float4 v = make_float4(tile[brow][c4*4+0], tile[brow][c4*4+1],
                               tile[brow][c4*4+2], tile[brow][c4*4+3]);
        ((float4*)y)[(size_t)(b0 + brow) * (T_LEN / 4) + t0 / 4 + c4] = v;
    }
}

extern "C" void kernel_launch(void* const* d_in, const int* in_sizes, int n_in,
                              void* d_out, int out_size, void* d_ws, size_t ws_size,
                              hipStream_t stream)
{
    (void)in_sizes; (void)n_in; (void)out_size; (void)ws_size;
    const float* x      = (const float*)d_in[0];
    const float* w_ih0  = (const float*)d_in[1];
    const float* w_hh0  = (const float*)d_in[2];
    const float* b_ih0  = (const float*)d_in[3];
    const float* b_hh0  = (const float*)d_in[4];
    const float* w_ih12 = (const float*)d_in[5];
    const float* w_hh12 = (const float*)d_in[6];
    const float* b_ih12 = (const float*)d_in[7];
    const float* b_hh12 = (const float*)d_in[8];
    const float* w_out  = (const float*)d_in[9];
    const float* b_out  = (const float*)d_in[10];
    float* y = (float*)d_out;

    // ws: xT [0,16.8MB) dead after layer0; l0out [33.5,67.1); l1out overlays xT
    // region [0,33.5); l2out overlays l0out [33.5,67.1).
    float* ws    = (float*)d_ws;
    float* xT    = ws;
    float* l0out = ws + (size_t)2 * B_SZ * T_LEN;
    float* l1out = ws;
    float* l2out = ws + (size_t)2 * B_SZ * T_LEN;

    const int nblk = 8 * S_CH;   // 2048
    k_tr     <<<1024, 256, 0, stream>>>(x, xT);
    k_scan0g <<<nblk, 64, 0, stream>>>(xT,    w_ih0,       w_hh0,      b_ih0,      b_hh0,      l0out);
    k_scan12g<<<nblk, 64, 0, stream>>>(l0out, w_ih12 + 0,  w_hh12 + 0, b_ih12 + 0, b_hh12 + 0, l1out);
    k_scan12g<<<nblk, 64, 0, stream>>>(l1out, w_ih12 + 12, w_hh12 + 6, b_ih12 + 6, b_hh12 + 6, l2out);
    k_proj   <<<1024, 256, 0, stream>>>(l2out, w_out, b_out, y);
}